// Round 2
// baseline (319.245 us; speedup 1.0000x reference)
//
#include <hip/hip_runtime.h>

#define S_LEN 4096
#define NBATCH 2
#define ROWS (NBATCH*S_LEN)          // 8192
#define OUT_ELEMS 2097152            // B*2*S*H

typedef _Float16 f16;
typedef _Float16 f16x8 __attribute__((ext_vector_type(8)));
typedef _Float16 f16x4 __attribute__((ext_vector_type(4)));
typedef float f32x4 __attribute__((ext_vector_type(4)));

// ---- workspace layout (bytes) ----
#define MT_OFF    0x000000   // 4 x 256x256 f16 (transposed M matrices)  512 KB
#define BIAS_OFF  0x080000   // 4 x 256 f32
#define SC_OFF    0x081000   // scalars: kc, nf2
#define QH_OFF    0x100000   // 8192x256 f16   4 MB
#define KH_OFF    0x500000   // 8192x256 f16   4 MB
#define VT_OFF    0x900000   // [b][256][4096] f16  4 MB
#define Q2_OFF    0xD00000   // 8192 f32
#define K2_OFF    0xD10000
#define L_OFF     0xD20000
#define EST_OFF   0xE00000   // 8192x256 f32   8 MB
#define WS_NEED   0x1600000  // 22 MB

#define MFMA16(A,B,C) __builtin_amdgcn_mfma_f32_16x16x32_f16(A,B,C,0,0,0)

__device__ __forceinline__ void async_cp16(f16* lds, const f16* g) {
  __builtin_amdgcn_global_load_lds(
      (const __attribute__((address_space(1))) void*)g,
      (__attribute__((address_space(3))) void*)lds, 16, 0, 0);
}

// stage 128x32 f16 tile (global row stride = stride elems) -> lds[128][32]
__device__ __forceinline__ void stage16(f16* lds, const f16* g, int stride, int tid) {
#pragma unroll
  for (int i = 0; i < 2; ++i) {
    int idx = i*256 + tid;
    int row = idx >> 2, c = idx & 3;
    async_cp16(lds + idx*8, g + (size_t)row*stride + c*8);
  }
}

// stage 128x32 f32 tile -> f16 lds[128][32] (convert)
__device__ __forceinline__ void stage32(f16* lds, const float* g, int stride, int tid) {
#pragma unroll
  for (int i = 0; i < 4; ++i) {
    int idx = i*256 + tid;
    int row = idx >> 3, c = idx & 7;
    const float4* gp = (const float4*)(g + (size_t)row*stride + c*4);
    float4 v = *gp;
    f16x4 h; h[0]=(f16)v.x; h[1]=(f16)v.y; h[2]=(f16)v.z; h[3]=(f16)v.w;
    *(f16x4*)(lds + row*32 + c*4) = h;
  }
}

// one BK=32 step: 4 A-frags, 4 B-frags, 16 MFMAs (wave covers 64x64 of 128x128)
__device__ __forceinline__ void mfma_step(const f16* Asm, const f16* Bsm, int lane,
                                          int wm, int wn, f32x4 acc[4][4]) {
  f16x8 a[4], b[4];
  int rr = lane & 15, kk = (lane >> 4) << 3;
#pragma unroll
  for (int i=0;i<4;i++) a[i] = *(const f16x8*)(Asm + (wm + i*16 + rr)*32 + kk);
#pragma unroll
  for (int j=0;j<4;j++) b[j] = *(const f16x8*)(Bsm + (wn + j*16 + rr)*32 + kk);
#pragma unroll
  for (int i=0;i<4;i++)
#pragma unroll
    for (int j=0;j<4;j++) acc[i][j] = MFMA16(a[i], b[j], acc[i][j]);
}

// ---- build combined complex-linear matrices Mt[n][k] = M[k][n], and biases ----
__global__ __launch_bounds__(256)
void k_build(const float* Wqr, const float* Wqi, const float* bqr, const float* bqi,
             const float* Wkr, const float* Wki, const float* bkr, const float* bki,
             const float* Wvr, const float* Wvi, const float* bvr, const float* bvi,
             const float* Wpr, const float* Wpi, const float* bpr, const float* bpi,
             f16* Mt, float* bias) {
  int mat = blockIdx.x;
  const float *Wr, *Wi, *br, *bi;
  if (mat == 0)      { Wr=Wqr; Wi=Wqi; br=bqr; bi=bqi; }
  else if (mat == 1) { Wr=Wkr; Wi=Wki; br=bkr; bi=bki; }
  else if (mat == 2) { Wr=Wvr; Wi=Wvi; br=bvr; bi=bvi; }
  else               { Wr=Wpr; Wi=Wpi; br=bpr; bi=bpi; }
  int idx = blockIdx.y*256 + threadIdx.x;
  int n = idx >> 8, k = idx & 255;
  int d = k & 127, h = n & 127;
  float w = (k < 128) ? ((n < 128) ? Wr[h*128+d] : Wi[h*128+d])
                      : ((n < 128) ? -Wi[h*128+d] : Wr[h*128+d]);
  Mt[mat*65536 + n*256 + k] = (f16)w;
  if (k == 0)
    bias[mat*256 + n] = (n < 128) ? (br[n] - bi[n]) : (br[n-128] + bi[n-128]);
}

// ---- zero est + lsum, compute scalars ----
__global__ __launch_bounds__(256)
void k_init(float* est, float* lsum, float* sc, const float* nf, const float* tau) {
  int idx = blockIdx.x*256 + threadIdx.x;   // float4 index
  if (idx < 524288) ((float4*)est)[idx] = make_float4(0.f,0.f,0.f,0.f);
  else { int j = idx - 524288; if (j < 2048) ((float4*)lsum)[j] = make_float4(0.f,0.f,0.f,0.f); }
  if (idx == 0) {
    // softplus(tau) = ln(1+e^t) = log2(1+2^(t*log2e)) * ln2  (hw exp2/log2 only)
    float t = tau[0];
    float c = __builtin_log2f(1.0f + __builtin_exp2f(t * 1.4426950408889634f))
              * 0.6931471805599453f;
    sc[0] = -c * 0.08838834764831845f;       // kc = -softplus(tau)/sqrt(128)
    sc[1] = nf[0]*nf[0] + 1e-6f;             // nf^2 + EPS
  }
}

// ---- projections: [zr|zi] @ Mt^T(+bias) -> Qh/Kh (rowmajor f16) or Vt (transposed) ----
__global__ __launch_bounds__(256)
void k_proj(const float* Zq, const float* Zk, const float* Zv,
            const f16* Mt, const float* bias,
            f16* Qh, f16* Kh, f16* Vt) {
  __shared__ f16 Asm[128*32];
  __shared__ f16 Bsm[128*32];
  __shared__ float bias_s[128];
  int tid = threadIdx.x;
  int mode = blockIdx.z;
  int m0 = blockIdx.x * 128, n0 = blockIdx.y * 128;
  const float* Z = (mode==0) ? Zq : (mode==1 ? Zk : Zv);
  const f16* Bt = Mt + mode*65536;
  if (tid < 128) bias_s[tid] = bias[mode*256 + n0 + tid];
  int b = m0 >> 12, s0 = m0 & 4095;
  int lane = tid & 63, w = tid >> 6;
  int wm = (w >> 1)*64, wn = (w & 1)*64;
  f32x4 acc[4][4] = {};
  for (int kb = 0; kb < 8; ++kb) {
    int k0 = kb*32;
    int part = k0 >> 7, d0 = k0 & 127;
    const float* Ag = Z + (((size_t)(b*2 + part))*S_LEN + s0)*128 + d0;
    stage32(Asm, Ag, 128, tid);
    stage16(Bsm, Bt + n0*256 + k0, 256, tid);
    __syncthreads();
    mfma_step(Asm, Bsm, lane, wm, wn, acc);
    __syncthreads();
  }
  int rr = (lane>>4)*4, cc = lane & 15;
  if (mode < 2) {
    f16* O = (mode==0) ? Qh : Kh;
#pragma unroll
    for (int i=0;i<4;i++)
#pragma unroll
      for (int j=0;j<4;j++) {
        int cl = wn + j*16 + cc;
        int cg = n0 + cl;
        float bv = bias_s[cl];
#pragma unroll
        for (int r=0;r<4;r++) {
          int rg = m0 + wm + i*16 + rr + r;
          O[(size_t)rg*256 + cg] = (f16)(acc[i][j][r] + bv);
        }
      }
  } else {
#pragma unroll
    for (int i=0;i<4;i++) {
      int t0 = s0 + wm + i*16 + rr;
#pragma unroll
      for (int j=0;j<4;j++) {
        int cl = wn + j*16 + cc;
        int cg = n0 + cl;
        float bv = bias_s[cl];
        f16x4 h4;
#pragma unroll
        for (int r=0;r<4;r++) h4[r] = (f16)(acc[i][j][r] + bv);
        *(f16x4*)(Vt + (size_t)b*1048576 + (size_t)cg*4096 + t0) = h4;
      }
    }
  }
}

// ---- q2/k2 from the f16 Q/K actually used in the MFMA (keeps R2 >= 0) ----
__global__ __launch_bounds__(256)
void k_sq(const f16* Qh, const f16* Kh, float* q2, float* k2) {
  int w = threadIdx.x >> 6, lane = threadIdx.x & 63;
  int rid = blockIdx.x*4 + w;  // 0..16383
  const f16* src = (rid < ROWS) ? Qh + (size_t)rid*256 : Kh + (size_t)(rid-ROWS)*256;
  f16x4 v = *(const f16x4*)(src + lane*4);
  float s = 0.f;
#pragma unroll
  for (int i=0;i<4;i++) { float f = (float)v[i]; s += f*f; }
#pragma unroll
  for (int m=32;m>=1;m>>=1) s += __shfl_xor(s, m, 64);
  if (lane==0) { if (rid < ROWS) q2[rid]=s; else k2[rid-ROWS]=s; }
}

// ---- QK^T tiles: WRITE=0 accumulate row sums, WRITE=1 write normalized attn ----
template<int WRITE>
__global__ __launch_bounds__(256)
void k_attn(const f16* Qh, const f16* Kh, const float* q2, const float* k2,
            const float* sc, float* lsum, float* attn) {
  __shared__ f16 Asm[128*32];
  __shared__ f16 Bsm[128*32];
  __shared__ float q2s[128], k2s[128], ls[128];
  int x = blockIdx.x;
  int b = x / 528, r = x % 528;
  int sb = (int)((__builtin_sqrtf(8.f*(float)r + 1.f) - 1.f)*0.5f);
  while ((sb+1)*(sb+2)/2 <= r) sb++;
  while (sb*(sb+1)/2 > r) sb--;
  int tb = r - sb*(sb+1)/2;
  int s0 = sb*128, t0 = tb*128;
  int tid = threadIdx.x;
  if (tid < 128) {
    q2s[tid] = q2[b*S_LEN + s0 + tid];
    k2s[tid] = k2[b*S_LEN + t0 + tid];
    if (WRITE) ls[tid] = 1.0f / lsum[b*S_LEN + s0 + tid];
  }
  float kc = sc[0], nf2 = sc[1];
  int lane = tid & 63, w = tid >> 6;
  int wm = (w >> 1)*64, wn = (w & 1)*64;
  const f16* Ag = Qh + ((size_t)(b*S_LEN) + s0)*256;
  const f16* Bg = Kh + ((size_t)(b*S_LEN) + t0)*256;
  f32x4 acc[4][4] = {};
  for (int kb=0;kb<8;kb++) {
    stage16(Asm, Ag + kb*32, 256, tid);
    stage16(Bsm, Bg + kb*32, 256, tid);
    __syncthreads();
    mfma_step(Asm, Bsm, lane, wm, wn, acc);
    __syncthreads();
  }
  int rr = (lane>>4)*4, cc = lane & 15;
  bool diag = (tb == sb);
  if (WRITE) {
#pragma unroll
    for (int i=0;i<4;i++)
#pragma unroll
      for (int j=0;j<4;j++) {
        int cl = wn + j*16 + cc;
        float kv = k2s[cl];
#pragma unroll
        for (int rg=0;rg<4;rg++) {
          int rl = wm + i*16 + rr + rg;
          float xx = nf2 + q2s[rl] + kv - 2.0f*acc[i][j][rg];
          float P = __builtin_exp2f(kc * __builtin_log2f(__builtin_fmaxf(xx, 1e-6f)));
          if (diag && (t0+cl) > (s0+rl)) P = 0.f;
          attn[((size_t)(b*S_LEN) + s0 + rl)*S_LEN + t0 + cl] = P * ls[rl];
        }
      }
  } else {
    float rs[4][4];
#pragma unroll
    for (int i=0;i<4;i++)
#pragma unroll
      for (int rg=0;rg<4;rg++) rs[i][rg]=0.f;
#pragma unroll
    for (int i=0;i<4;i++)
#pragma unroll
      for (int j=0;j<4;j++) {
        int cl = wn + j*16 + cc;
        float kv = k2s[cl];
#pragma unroll
        for (int rg=0;rg<4;rg++) {
          int rl = wm + i*16 + rr + rg;
          float xx = nf2 + q2s[rl] + kv - 2.0f*acc[i][j][rg];
          float P = __builtin_exp2f(kc * __builtin_log2f(__builtin_fmaxf(xx, 1e-6f)));
          if (diag && (t0+cl) > (s0+rl)) P = 0.f;
          rs[i][rg] += P;
        }
      }
#pragma unroll
    for (int m=8;m>=1;m>>=1)
#pragma unroll
      for (int i=0;i<4;i++)
#pragma unroll
        for (int rg=0;rg<4;rg++) rs[i][rg] += __shfl_xor(rs[i][rg], m, 64);
    if (cc == 0)
#pragma unroll
      for (int i=0;i<4;i++)
#pragma unroll
        for (int rg=0;rg<4;rg++) {
          int rl = wm + i*16 + rr + rg;
          atomicAdd(&lsum[b*S_LEN + s0 + rl], rs[i][rg]);
        }
  }
}

// ---- zero the strictly-upper (t >= next 128-block) region of attn ----
__global__ __launch_bounds__(256)
void k_zupper(float* attn) {
  int rid = blockIdx.x;               // 0..8191
  int b = rid >> 12, s = rid & 4095;
  int tstart = ((s >> 7) + 1) << 7;
  float4* p = (float4*)(attn + ((size_t)(b*S_LEN) + s)*S_LEN);
  for (int i = (tstart >> 2) + threadIdx.x; i < 1024; i += 256)
    p[i] = make_float4(0.f,0.f,0.f,0.f);
}

// ---- PV: est += attn @ V  (split-K over 8-tile t-chunks, atomicAdd) ----
__global__ __launch_bounds__(256)
void k_pv(const float* attn, const f16* Vt, float* est) {
  __shared__ f16 Asm[128*32];
  __shared__ f16 Bsm[128*32];
  int sb = blockIdx.x, nb = blockIdx.y, z = blockIdx.z;
  int b = z >> 2, tc = z & 3;
  if (tc > (sb >> 3)) return;
  int s0 = sb*128, h0 = nb*128;
  int tid = threadIdx.x;
  int lane = tid & 63, w = tid >> 6;
  int wm = (w>>1)*64, wn = (w&1)*64;
  int tb1 = tc*8 + 8; if (tb1 > sb+1) tb1 = sb+1;
  const float* Abase = attn + ((size_t)(b*S_LEN) + s0)*S_LEN;
  const f16* Bbase = Vt + (size_t)b*1048576 + (size_t)h0*4096;
  f32x4 acc[4][4] = {};
  for (int tb = tc*8; tb < tb1; ++tb)
    for (int kk = 0; kk < 4; ++kk) {
      int t0 = tb*128 + kk*32;
      stage32(Asm, Abase + t0, S_LEN, tid);
      stage16(Bsm, Bbase + t0, 4096, tid);
      __syncthreads();
      mfma_step(Asm, Bsm, lane, wm, wn, acc);
      __syncthreads();
    }
  int rr = (lane>>4)*4, cc = lane & 15;
#pragma unroll
  for (int i=0;i<4;i++)
#pragma unroll
    for (int j=0;j<4;j++) {
      int cg = h0 + wn + j*16 + cc;
#pragma unroll
      for (int rg=0;rg<4;rg++) {
        int rgl = s0 + wm + i*16 + rr + rg;
        atomicAdd(&est[((size_t)(b*S_LEN) + rgl)*256 + cg], acc[i][j][rg]);
      }
    }
}

// ---- output projection: out = est @ Mp + bias, split into (b,comp,s,h) layout ----
__global__ __launch_bounds__(256)
void k_out(const float* est, const f16* Mt, const float* bias, float* outp) {
  __shared__ f16 Asm[128*32];
  __shared__ f16 Bsm[128*32];
  __shared__ float bias_s[128];
  int m0 = blockIdx.x*128, n0 = blockIdx.y*128;
  int tid = threadIdx.x;
  if (tid < 128) bias_s[tid] = bias[3*256 + n0 + tid];
  int lane = tid & 63, w = tid >> 6;
  int wm = (w>>1)*64, wn = (w&1)*64;
  const f16* Bt = Mt + 3*65536;
  f32x4 acc[4][4] = {};
  for (int kb=0;kb<8;kb++) {
    stage32(Asm, est + (size_t)m0*256 + kb*32, 256, tid);
    stage16(Bsm, Bt + n0*256 + kb*32, 256, tid);
    __syncthreads();
    mfma_step(Asm, Bsm, lane, wm, wn, acc);
    __syncthreads();
  }
  int rr = (lane>>4)*4, cc = lane & 15;
  int b = m0 >> 12, s0 = m0 & 4095;
#pragma unroll
  for (int i=0;i<4;i++)
#pragma unroll
    for (int j=0;j<4;j++) {
      int cl = wn + j*16 + cc;
      int cg = n0 + cl;
      int comp = cg >> 7, h = cg & 127;
      float bv = bias_s[cl];
#pragma unroll
      for (int rg=0;rg<4;rg++) {
        int s = s0 + wm + i*16 + rr + rg;
        outp[(((size_t)(b*2 + comp))*S_LEN + s)*128 + h] = acc[i][j][rg] + bv;
      }
    }
}

extern "C" void kernel_launch(void* const* d_in, const int* in_sizes, int n_in,
                              void* d_out, int out_size, void* d_ws, size_t ws_size,
                              hipStream_t stream) {
  (void)in_sizes; (void)n_in; (void)out_size;
  if (ws_size < (size_t)WS_NEED) return;  // fail loudly (output stays poisoned)
  const float* Zq = (const float*)d_in[0];
  const float* Zk = (const float*)d_in[1];
  const float* Zv = (const float*)d_in[2];
  char* ws = (char*)d_ws;
  f16*   Mt   = (f16*)(ws + MT_OFF);
  float* bias = (float*)(ws + BIAS_OFF);
  float* sc   = (float*)(ws + SC_OFF);
  f16*   Qh   = (f16*)(ws + QH_OFF);
  f16*   Kh   = (f16*)(ws + KH_OFF);
  f16*   Vt   = (f16*)(ws + VT_OFF);
  float* q2   = (float*)(ws + Q2_OFF);
  float* k2   = (float*)(ws + K2_OFF);
  float* lsum = (float*)(ws + L_OFF);
  float* est  = (float*)(ws + EST_OFF);
  float* outp = (float*)d_out;
  float* attn = outp + OUT_ELEMS;

  k_build<<<dim3(4,256), 256, 0, stream>>>(
      (const float*)d_in[3],  (const float*)d_in[4],  (const float*)d_in[5],  (const float*)d_in[6],
      (const float*)d_in[7],  (const float*)d_in[8],  (const float*)d_in[9],  (const float*)d_in[10],
      (const float*)d_in[11], (const float*)d_in[12], (const float*)d_in[13], (const float*)d_in[14],
      (const float*)d_in[15], (const float*)d_in[16], (const float*)d_in[17], (const float*)d_in[18],
      Mt, bias);
  k_init<<<2056, 256, 0, stream>>>(est, lsum, sc, (const float*)d_in[19], (const float*)d_in[20]);
  k_proj<<<dim3(64,2,3), 256, 0, stream>>>(Zq, Zk, Zv, Mt, bias, Qh, Kh, Vt);
  k_sq<<<4096, 256, 0, stream>>>(Qh, Kh, q2, k2);
  k_attn<0><<<1056, 256, 0, stream>>>(Qh, Kh, q2, k2, sc, lsum, attn);
  k_attn<1><<<1056, 256, 0, stream>>>(Qh, Kh, q2, k2, sc, lsum, attn);
  k_zupper<<<8192, 256, 0, stream>>>(attn);
  k_pv<<<dim3(32,2,8), 256, 0, stream>>>(attn, Vt, est);
  k_out<<<dim3(64,2), 256, 0, stream>>>(est, Mt, bias, outp);
}

// Round 3
// 302.054 us; speedup vs baseline: 1.0569x; 1.0569x over previous
//
#include <hip/hip_runtime.h>

#define S_LEN 4096
#define NBATCH 2
#define ROWS (NBATCH*S_LEN)          // 8192
#define OUT_ELEMS 2097152            // B*2*S*H

typedef _Float16 f16;
typedef _Float16 f16x8 __attribute__((ext_vector_type(8)));
typedef _Float16 f16x4 __attribute__((ext_vector_type(4)));
typedef float f32x4 __attribute__((ext_vector_type(4)));

// ---- workspace layout (bytes) ----
#define MT_OFF    0x000000   // 4 x 256x256 f16 (transposed M matrices)  512 KB
#define BIAS_OFF  0x080000   // 4 x 256 f32
#define SC_OFF    0x081000   // scalars: kc, nf2
#define QH_OFF    0x100000   // 8192x256 f16   4 MB
#define KH_OFF    0x500000   // 8192x256 f16   4 MB
#define VT_OFF    0x900000   // [b][256][4096] f16  4 MB
#define Q2_OFF    0xD00000   // 8192 f32 (q2, k2, lsum share a 192KB zeroed region)
#define K2_OFF    0xD10000
#define L_OFF     0xD20000
#define EST_OFF   0xE00000   // 8192x256 f32   8 MB
#define PW_OFF    0x1600000  // [b][4096][4096] f16 unnormalized P   64 MB
#define WS_NEED   0x5600000  // ~90 MB (poison fill shows ws ~544 MiB)

#define MFMA16(A,B,C) __builtin_amdgcn_mfma_f32_16x16x32_f16(A,B,C,0,0,0)

__device__ __forceinline__ void async_cp16(f16* lds, const f16* g) {
  __builtin_amdgcn_global_load_lds(
      (const __attribute__((address_space(1))) void*)g,
      (__attribute__((address_space(3))) void*)lds, 16, 0, 0);
}

// stage 128x32 f16 tile (global row stride = stride elems) -> lds[128][32]
__device__ __forceinline__ void stage16(f16* lds, const f16* g, int stride, int tid) {
#pragma unroll
  for (int i = 0; i < 2; ++i) {
    int idx = i*256 + tid;
    int row = idx >> 2, c = idx & 3;
    async_cp16(lds + idx*8, g + (size_t)row*stride + c*8);
  }
}

// stage 128x32 f32 tile -> f16 lds[128][32] (convert), optional per-row scale
__device__ __forceinline__ void stage32(f16* lds, const float* g, int stride, int tid,
                                        const float* rowscale) {
#pragma unroll
  for (int i = 0; i < 4; ++i) {
    int idx = i*256 + tid;
    int row = idx >> 3, c = idx & 7;
    const float4* gp = (const float4*)(g + (size_t)row*stride + c*4);
    float4 v = *gp;
    float sc = rowscale ? rowscale[row] : 1.0f;
    f16x4 h; h[0]=(f16)(v.x*sc); h[1]=(f16)(v.y*sc); h[2]=(f16)(v.z*sc); h[3]=(f16)(v.w*sc);
    *(f16x4*)(lds + row*32 + c*4) = h;
  }
}

// one BK=32 step: 4 A-frags, 4 B-frags, 16 MFMAs (wave covers 64x64 of 128x128)
__device__ __forceinline__ void mfma_step(const f16* Asm, const f16* Bsm, int lane,
                                          int wm, int wn, f32x4 acc[4][4]) {
  f16x8 a[4], b[4];
  int rr = lane & 15, kk = (lane >> 4) << 3;
#pragma unroll
  for (int i=0;i<4;i++) a[i] = *(const f16x8*)(Asm + (wm + i*16 + rr)*32 + kk);
#pragma unroll
  for (int j=0;j<4;j++) b[j] = *(const f16x8*)(Bsm + (wn + j*16 + rr)*32 + kk);
#pragma unroll
  for (int i=0;i<4;i++)
#pragma unroll
    for (int j=0;j<4;j++) acc[i][j] = MFMA16(a[i], b[j], acc[i][j]);
}

// ---- build combined complex-linear matrices Mt[n][k] = M[k][n], and biases ----
__global__ __launch_bounds__(256)
void k_build(const float* Wqr, const float* Wqi, const float* bqr, const float* bqi,
             const float* Wkr, const float* Wki, const float* bkr, const float* bki,
             const float* Wvr, const float* Wvi, const float* bvr, const float* bvi,
             const float* Wpr, const float* Wpi, const float* bpr, const float* bpi,
             f16* Mt, float* bias) {
  int mat = blockIdx.x;
  const float *Wr, *Wi, *br, *bi;
  if (mat == 0)      { Wr=Wqr; Wi=Wqi; br=bqr; bi=bqi; }
  else if (mat == 1) { Wr=Wkr; Wi=Wki; br=bkr; bi=bki; }
  else if (mat == 2) { Wr=Wvr; Wi=Wvi; br=bvr; bi=bvi; }
  else               { Wr=Wpr; Wi=Wpi; br=bpr; bi=bpi; }
  int idx = blockIdx.y*256 + threadIdx.x;
  int n = idx >> 8, k = idx & 255;
  int d = k & 127, h = n & 127;
  float w = (k < 128) ? ((n < 128) ? Wr[h*128+d] : Wi[h*128+d])
                      : ((n < 128) ? -Wi[h*128+d] : Wr[h*128+d]);
  Mt[mat*65536 + n*256 + k] = (f16)w;
  if (k == 0)
    bias[mat*256 + n] = (n < 128) ? (br[n] - bi[n]) : (br[n-128] + bi[n-128]);
}

// ---- zero est + q2/k2/lsum region, compute scalars ----
__global__ __launch_bounds__(256)
void k_init(float* est, float* zreg, float* sc, const float* nf, const float* tau) {
  int idx = blockIdx.x*256 + threadIdx.x;   // float4 index
  if (idx < 524288) ((float4*)est)[idx] = make_float4(0.f,0.f,0.f,0.f);
  else { int j = idx - 524288; if (j < 12288) ((float4*)zreg)[j] = make_float4(0.f,0.f,0.f,0.f); }
  if (idx == 0) {
    float t = tau[0];
    float c = __builtin_log2f(1.0f + __builtin_exp2f(t * 1.4426950408889634f))
              * 0.6931471805599453f;        // softplus(tau)
    sc[0] = -c * 0.08838834764831845f;       // kc = -softplus(tau)/sqrt(128)
    sc[1] = nf[0]*nf[0] + 1e-6f;             // nf^2 + EPS
  }
}

// ---- projections + fused |row|^2 for Q/K (squares of the f16-rounded values) ----
__global__ __launch_bounds__(256)
void k_proj(const float* Zq, const float* Zk, const float* Zv,
            const f16* Mt, const float* bias,
            f16* Qh, f16* Kh, f16* Vt, float* q2, float* k2) {
  __shared__ f16 Asm[128*32];
  __shared__ f16 Bsm[128*32];
  __shared__ float bias_s[128];
  int tid = threadIdx.x;
  int mode = blockIdx.z;
  int m0 = blockIdx.x * 128, n0 = blockIdx.y * 128;
  const float* Z = (mode==0) ? Zq : (mode==1 ? Zk : Zv);
  const f16* Bt = Mt + mode*65536;
  if (tid < 128) bias_s[tid] = bias[mode*256 + n0 + tid];
  int b = m0 >> 12, s0 = m0 & 4095;
  int lane = tid & 63, w = tid >> 6;
  int wm = (w >> 1)*64, wn = (w & 1)*64;
  f32x4 acc[4][4] = {};
  for (int kb = 0; kb < 8; ++kb) {
    int k0 = kb*32;
    int part = k0 >> 7, d0 = k0 & 127;
    const float* Ag = Z + (((size_t)(b*2 + part))*S_LEN + s0)*128 + d0;
    stage32(Asm, Ag, 128, tid, nullptr);
    stage16(Bsm, Bt + n0*256 + k0, 256, tid);
    __syncthreads();
    mfma_step(Asm, Bsm, lane, wm, wn, acc);
    __syncthreads();
  }
  int rr = (lane>>4)*4, cc = lane & 15;
  if (mode < 2) {
    f16* O = (mode==0) ? Qh : Kh;
    float rs[4][4];
#pragma unroll
    for (int i=0;i<4;i++)
#pragma unroll
      for (int r=0;r<4;r++) rs[i][r]=0.f;
#pragma unroll
    for (int i=0;i<4;i++)
#pragma unroll
      for (int j=0;j<4;j++) {
        int cl = wn + j*16 + cc;
        int cg = n0 + cl;
        float bv = bias_s[cl];
#pragma unroll
        for (int r=0;r<4;r++) {
          int rg = m0 + wm + i*16 + rr + r;
          f16 hv = (f16)(acc[i][j][r] + bv);
          O[(size_t)rg*256 + cg] = hv;
          float fv = (float)hv;
          rs[i][r] += fv*fv;
        }
      }
    // reduce across cc lanes (bits 0..3) and atomically add the half-row sums
#pragma unroll
    for (int m=8;m>=1;m>>=1)
#pragma unroll
      for (int i=0;i<4;i++)
#pragma unroll
        for (int r=0;r<4;r++) rs[i][r] += __shfl_xor(rs[i][r], m, 64);
    if (cc == 0) {
      float* T = (mode==0) ? q2 : k2;
#pragma unroll
      for (int i=0;i<4;i++)
#pragma unroll
        for (int r=0;r<4;r++) {
          int rg = m0 + wm + i*16 + rr + r;
          atomicAdd(&T[rg], rs[i][r]);
        }
    }
  } else {
#pragma unroll
    for (int i=0;i<4;i++) {
      int t0 = s0 + wm + i*16 + rr;
#pragma unroll
      for (int j=0;j<4;j++) {
        int cl = wn + j*16 + cc;
        int cg = n0 + cl;
        float bv = bias_s[cl];
        f16x4 h4;
#pragma unroll
        for (int r=0;r<4;r++) h4[r] = (f16)(acc[i][j][r] + bv);
        *(f16x4*)(Vt + (size_t)b*1048576 + (size_t)cg*4096 + t0) = h4;
      }
    }
  }
}

// ---- single QK pass over the full square: lower tiles compute unnormalized P
//      (f16 -> Pws) + atomic lsum; upper tiles write zeros to d_out attn ----
__global__ __launch_bounds__(256)
void k_attn(const f16* Qh, const f16* Kh, const float* q2, const float* k2,
            const float* sc, float* lsum, f16* Pws, float* attn) {
  int x = blockIdx.x;
  int b = x >> 10, r = x & 1023;
  int sb = r >> 5, tb = r & 31;
  int s0 = sb*128, t0 = tb*128;
  int tid = threadIdx.x;
  if (tb > sb) {   // strictly-upper tile: zeros straight to output
    float4 z = make_float4(0.f,0.f,0.f,0.f);
    int row = tid >> 1, h = tid & 1;
    float4* p = (float4*)(attn + ((size_t)(b*S_LEN) + s0 + row)*S_LEN + t0 + h*64);
#pragma unroll
    for (int i=0;i<16;i++) p[i] = z;
    return;
  }
  __shared__ f16 Asm[128*32];
  __shared__ f16 Bsm[128*32];
  __shared__ float q2s[128], k2s[128];
  if (tid < 128) {
    q2s[tid] = q2[b*S_LEN + s0 + tid];
    k2s[tid] = k2[b*S_LEN + t0 + tid];
  }
  float kc = sc[0], nf2 = sc[1];
  int lane = tid & 63, w = tid >> 6;
  int wm = (w >> 1)*64, wn = (w & 1)*64;
  const f16* Ag = Qh + ((size_t)(b*S_LEN) + s0)*256;
  const f16* Bg = Kh + ((size_t)(b*S_LEN) + t0)*256;
  f32x4 acc[4][4] = {};
  for (int kb=0;kb<8;kb++) {
    stage16(Asm, Ag + kb*32, 256, tid);
    stage16(Bsm, Bg + kb*32, 256, tid);
    __syncthreads();
    mfma_step(Asm, Bsm, lane, wm, wn, acc);
    __syncthreads();
  }
  int rr = (lane>>4)*4, cc = lane & 15;
  bool diag = (tb == sb);
  float rs[4][4];
#pragma unroll
  for (int i=0;i<4;i++)
#pragma unroll
    for (int rg=0;rg<4;rg++) rs[i][rg]=0.f;
#pragma unroll
  for (int i=0;i<4;i++)
#pragma unroll
    for (int j=0;j<4;j++) {
      int cl = wn + j*16 + cc;
      float kv = k2s[cl];
#pragma unroll
      for (int rg=0;rg<4;rg++) {
        int rl = wm + i*16 + rr + rg;
        float xx = nf2 + q2s[rl] + kv - 2.0f*acc[i][j][rg];
        float P = __builtin_exp2f(kc * __builtin_log2f(__builtin_fmaxf(xx, 1e-6f)));
        if (diag && (t0+cl) > (s0+rl)) P = 0.f;
        Pws[((size_t)(b*S_LEN) + s0 + rl)*S_LEN + t0 + cl] = (f16)P;
        rs[i][rg] += P;
      }
    }
#pragma unroll
  for (int m=8;m>=1;m>>=1)
#pragma unroll
    for (int i=0;i<4;i++)
#pragma unroll
      for (int rg=0;rg<4;rg++) rs[i][rg] += __shfl_xor(rs[i][rg], m, 64);
  if (cc == 0)
#pragma unroll
    for (int i=0;i<4;i++)
#pragma unroll
      for (int rg=0;rg<4;rg++) {
        int rl = wm + i*16 + rr + rg;
        atomicAdd(&lsum[b*S_LEN + s0 + rl], rs[i][rg]);
      }
}

// ---- PV: est_unnorm += P @ V (uniform 4-tile chunks, fp32 atomics);
//      h-half-0 blocks also emit the normalized fp32 attn tiles ----
__global__ __launch_bounds__(256)
void k_pv(const f16* Pws, const f16* Vt, const float* lsum, float* est, float* attn) {
  __shared__ f16 Asm[128*32];
  __shared__ f16 Bsm[128*32];
  __shared__ float ls[128];
  int r = blockIdx.x;                 // 0..143 -> (sb, chunk)
  int nb = blockIdx.y, b = blockIdx.z;
  int sb = 0;
  while (r >= ((sb+4)>>2)) { r -= (sb+4)>>2; sb++; }
  int c = r;
  int s0 = sb*128, h0 = nb*128;
  int tid = threadIdx.x;
  bool wrb = (nb == 0);
  if (wrb && tid < 128) ls[tid] = 1.0f / lsum[b*S_LEN + s0 + tid];
  int lane = tid & 63, w = tid >> 6;
  int wm = (w>>1)*64, wn = (w&1)*64;
  int tb0 = c*4, tb1 = tb0 + 4; if (tb1 > sb+1) tb1 = sb+1;
  const f16* Abase = Pws + ((size_t)(b*S_LEN) + s0)*S_LEN;
  const f16* Bbase = Vt + (size_t)b*1048576 + (size_t)h0*4096;
  f32x4 acc[4][4] = {};
  int row2 = tid >> 1, half2 = tid & 1;
  for (int tb = tb0; tb < tb1; ++tb)
    for (int kk = 0; kk < 4; ++kk) {
      int t0 = tb*128 + kk*32;
      stage16(Asm, Abase + t0, S_LEN, tid);
      stage16(Bsm, Bbase + t0, 4096, tid);
      __syncthreads();
      if (wrb) {   // normalized attn tile chunk: LDS f16 -> *1/l -> fp32 out
        float invl = ls[row2];
        const f16x8* src = (const f16x8*)(Asm + row2*32 + half2*16);
        f16x8 v0 = src[0], v1 = src[1];
        float4* dst = (float4*)(attn + ((size_t)(b*S_LEN) + s0 + row2)*S_LEN + t0 + half2*16);
        float4 o;
        o.x=(float)v0[0]*invl; o.y=(float)v0[1]*invl; o.z=(float)v0[2]*invl; o.w=(float)v0[3]*invl; dst[0]=o;
        o.x=(float)v0[4]*invl; o.y=(float)v0[5]*invl; o.z=(float)v0[6]*invl; o.w=(float)v0[7]*invl; dst[1]=o;
        o.x=(float)v1[0]*invl; o.y=(float)v1[1]*invl; o.z=(float)v1[2]*invl; o.w=(float)v1[3]*invl; dst[2]=o;
        o.x=(float)v1[4]*invl; o.y=(float)v1[5]*invl; o.z=(float)v1[6]*invl; o.w=(float)v1[7]*invl; dst[3]=o;
      }
      mfma_step(Asm, Bsm, lane, wm, wn, acc);
      __syncthreads();
    }
  int rr = (lane>>4)*4, cc = lane & 15;
#pragma unroll
  for (int i=0;i<4;i++)
#pragma unroll
    for (int j=0;j<4;j++) {
      int cg = h0 + wn + j*16 + cc;
#pragma unroll
      for (int rg=0;rg<4;rg++) {
        int rgl = s0 + wm + i*16 + rr + rg;
        atomicAdd(&est[((size_t)(b*S_LEN) + rgl)*256 + cg], acc[i][j][rg]);
      }
    }
}

// ---- output projection: out = (est * 1/l rows) @ Mp + bias ----
__global__ __launch_bounds__(256)
void k_out(const float* est, const f16* Mt, const float* bias, const float* lsum,
           float* outp) {
  __shared__ f16 Asm[128*32];
  __shared__ f16 Bsm[128*32];
  __shared__ float bias_s[128];
  __shared__ float ls[128];
  int m0 = blockIdx.x*128, n0 = blockIdx.y*128;
  int tid = threadIdx.x;
  int b = m0 >> 12, s0 = m0 & 4095;
  if (tid < 128) {
    bias_s[tid] = bias[3*256 + n0 + tid];
    ls[tid] = 1.0f / lsum[b*S_LEN + s0 + tid];
  }
  __syncthreads();
  int lane = tid & 63, w = tid >> 6;
  int wm = (w>>1)*64, wn = (w&1)*64;
  const f16* Bt = Mt + 3*65536;
  f32x4 acc[4][4] = {};
  for (int kb=0;kb<8;kb++) {
    stage32(Asm, est + (size_t)m0*256 + kb*32, 256, tid, ls);
    stage16(Bsm, Bt + n0*256 + kb*32, 256, tid);
    __syncthreads();
    mfma_step(Asm, Bsm, lane, wm, wn, acc);
    __syncthreads();
  }
  int rr = (lane>>4)*4, cc = lane & 15;
#pragma unroll
  for (int i=0;i<4;i++)
#pragma unroll
    for (int j=0;j<4;j++) {
      int cl = wn + j*16 + cc;
      int cg = n0 + cl;
      int comp = cg >> 7, h = cg & 127;
      float bv = bias_s[cl];
#pragma unroll
      for (int rg=0;rg<4;rg++) {
        int s = s0 + wm + i*16 + rr + rg;
        outp[(((size_t)(b*2 + comp))*S_LEN + s)*128 + h] = acc[i][j][rg] + bv;
      }
    }
}

extern "C" void kernel_launch(void* const* d_in, const int* in_sizes, int n_in,
                              void* d_out, int out_size, void* d_ws, size_t ws_size,
                              hipStream_t stream) {
  (void)in_sizes; (void)n_in; (void)out_size;
  if (ws_size < (size_t)WS_NEED) return;  // fail loudly (output stays poisoned)
  const float* Zq = (const float*)d_in[0];
  const float* Zk = (const float*)d_in[1];
  const float* Zv = (const float*)d_in[2];
  char* ws = (char*)d_ws;
  f16*   Mt   = (f16*)(ws + MT_OFF);
  float* bias = (float*)(ws + BIAS_OFF);
  float* sc   = (float*)(ws + SC_OFF);
  f16*   Qh   = (f16*)(ws + QH_OFF);
  f16*   Kh   = (f16*)(ws + KH_OFF);
  f16*   Vt   = (f16*)(ws + VT_OFF);
  float* q2   = (float*)(ws + Q2_OFF);
  float* k2   = (float*)(ws + K2_OFF);
  float* lsum = (float*)(ws + L_OFF);
  float* est  = (float*)(ws + EST_OFF);
  f16*   Pws  = (f16*)(ws + PW_OFF);
  float* outp = (float*)d_out;
  float* attn = outp + OUT_ELEMS;

  k_build<<<dim3(4,256), 256, 0, stream>>>(
      (const float*)d_in[3],  (const float*)d_in[4],  (const float*)d_in[5],  (const float*)d_in[6],
      (const float*)d_in[7],  (const float*)d_in[8],  (const float*)d_in[9],  (const float*)d_in[10],
      (const float*)d_in[11], (const float*)d_in[12], (const float*)d_in[13], (const float*)d_in[14],
      (const float*)d_in[15], (const float*)d_in[16], (const float*)d_in[17], (const float*)d_in[18],
      Mt, bias);
  k_init<<<2096, 256, 0, stream>>>(est, q2, sc, (const float*)d_in[19], (const float*)d_in[20]);
  k_proj<<<dim3(64,2,3), 256, 0, stream>>>(Zq, Zk, Zv, Mt, bias, Qh, Kh, Vt, q2, k2);
  k_attn<<<2048, 256, 0, stream>>>(Qh, Kh, q2, k2, sc, lsum, Pws, attn);
  k_pv<<<dim3(144,2,2), 256, 0, stream>>>(Pws, Vt, lsum, est, attn);
  k_out<<<dim3(64,2), 256, 0, stream>>>(est, Mt, bias, lsum, outp);
}